// Round 12
// baseline (230.320 us; speedup 1.0000x reference)
//
#include <hip/hip_runtime.h>
#include <hip/hip_bf16.h>

#define NT      8
#define TD      100
#define FEAT    172
#define DIN     272     // FEAT + TD
#define KPAD    288     // padded K, 9 * 32
#define NKS     9       // KPAD / 32
#define OUTD    128
#define BM      32      // rows per MFMA sub-tile (2 rowblocks of 16)
#define WIN     256     // edges per block (8 sub-tiles)
#define NST     (WIN / BM)
#define TWO_PI  6.283185307179586

typedef __bf16 bf16x8 __attribute__((ext_vector_type(8)));
typedef float  f32x4  __attribute__((ext_vector_type(4)));
typedef short  s16x8  __attribute__((ext_vector_type(8)));

__device__ __forceinline__ unsigned short f2bf(float f) {
    __hip_bfloat16 h = __float2bfloat16(f);        // 1-op HW convert (RNE)
    return __builtin_bit_cast(unsigned short, h);
}

// ---------------- dtype detection (int32 vs int64 edge_types) ----------------
__global__ void k_detect(const int* __restrict__ words, int* __restrict__ flag) {
    __shared__ int s_or;
    if (threadIdx.x == 0) s_or = 0;
    __syncthreads();
    int v  = words[2 * threadIdx.x + 1];
    int v2 = words[2 * (threadIdx.x + 256) + 1];
    if (v | v2) atomicOr(&s_or, 1);
    __syncthreads();
    if (threadIdx.x == 0) *flag = (s_or == 0) ? 1 : 0;   // 1 => int64
}

__device__ __forceinline__ int get_type(const int* __restrict__ p, int e, int is64) {
    return p[is64 ? (2 * e) : e] & 7;
}

// ---------------- table prep ----------------
__global__ void k_prep_tables(const float* __restrict__ b, const float* __restrict__ temb,
                              float* __restrict__ freq_base, float* __restrict__ bias) {
    int gid = blockIdx.x * blockDim.x + threadIdx.x;
    if (gid < TD)
        freq_base[gid] = (float)(pow(10.0, -(double)gid / 11.0) / TWO_PI);
    if (gid < NT * OUTD) bias[gid] = b[gid] + temb[gid];
}

// W[t][k][n] fp32 -> bf16 fragment order: bfrag[(((t*NKS+s)*8+nf)*64+lane)*8+i]
// lane: col = nf*16 + (lane&15), k = s*32 + (lane>>4)*8 + i   [HW-verified R3/R6]
__global__ void k_prep_bfrag(const float* __restrict__ W, unsigned short* __restrict__ bfrag) {
    int gid = blockIdx.x * blockDim.x + threadIdx.x;
    if (gid >= NT * NKS * 8 * 64) return;
    int lane = gid & 63;
    int rest = gid >> 6;
    int nf = rest & 7; rest >>= 3;
    int s = rest % NKS, t = rest / NKS;
    int n  = nf * 16 + (lane & 15);
    int kb = s * 32 + (lane >> 4) * 8;
    unsigned short v[8];
    #pragma unroll
    for (int i = 0; i < 8; ++i) {
        int k = kb + i;
        float x = (k < DIN) ? W[((size_t)t * DIN + k) * OUTD + n] : 0.0f;
        v[i] = f2bf(x);
    }
    unsigned short* dst = bfrag + (size_t)gid * 8;
    #pragma unroll
    for (int i = 0; i < 8; ++i) dst[i] = v[i];
}

// ---------------- main kernel: 512 threads, 2 wave-groups ping-pong ----------------
// Window = 256 consecutive edges, counting-sorted by type in LDS.
// Group g (waves 4g..4g+3) owns a_lds[g] and subtiles {g, g+2, g+4, g+6}:
// step i: group (i&1) stages subtile i  ||  group ((i-1)&1) MFMAs subtile i-1.
__global__ __launch_bounds__(512, 6) void k_main(
    const float* __restrict__ feats, const float* __restrict__ ts,
    const int* __restrict__ types, const int* __restrict__ flag,
    float* __restrict__ out, const float* __restrict__ freq_base,
    const float* __restrict__ bias_tab, const unsigned short* __restrict__ bfrag,
    int E)
{
    __shared__ __align__(16) unsigned short a_lds[2][2 * NKS * 64 * 8]; // 2x18432 B
    __shared__ unsigned short pt[WIN];   // local_idx(8b) | type<<12 ; 0xFFFF invalid
    __shared__ float tsm[WIN];           // ts[e] * (1 + 0.1*t), by sorted slot
    __shared__ float freq_lds[TD];
    __shared__ int cnt[NT];
    __shared__ int seg[NT + 1];
    __shared__ int um[NST];              // per-sub-tile type union mask

    const int tid = threadIdx.x;
    const long base_e = (long)blockIdx.x * WIN;
    const int is64 = *flag;

    if (tid < NT)  cnt[tid] = 0;
    if (tid < NST) um[tid] = 0;
    if (tid < TD)  freq_lds[tid] = freq_base[tid];
    if (tid < WIN) { pt[tid] = 0xFFFF; tsm[tid] = 0.0f; }
    __syncthreads();

    // counting sort (threads 0..255 handle one edge each)
    int t0 = -1; float f0 = 0.f;
    if (tid < WIN) {
        long e0 = base_e + tid;
        if (e0 < (long)E) {
            t0 = get_type(types, (int)e0, is64);
            f0 = ts[e0] * (1.0f + 0.1f * (float)t0);
            atomicAdd(&cnt[t0], 1);
        }
    }
    __syncthreads();
    if (tid == 0) {
        int a = 0;
        #pragma unroll
        for (int t = 0; t < NT; ++t) { seg[t] = a; a += cnt[t]; cnt[t] = 0; }
        seg[NT] = a;
    }
    __syncthreads();
    if (t0 >= 0) {
        int r = seg[t0] + atomicAdd(&cnt[t0], 1);
        pt[r] = (unsigned short)(tid | (t0 << 12));
        tsm[r] = f0;
        atomicOr(&um[r >> 5], 1 << t0);
    }
    __syncthreads();

    const int g    = tid >> 8;          // wave-group 0/1
    const int tg   = tid & 255;         // thread within group
    const int w    = (tid >> 6) & 3;    // wave within group
    const int lane = tid & 63;
    const int hq = lane >> 4, l15 = lane & 15;
    const int col0 = w * 32 + l15;      // nf = 2w
    const int col1 = col0 + 16;         // nf = 2w+1

    #pragma unroll 1
    for (int i = 0; i <= NST; ++i) {
        // ================= STAGE subtile i (group i&1) =================
        if (i < NST && (i & 1) == g) {
            unsigned short* A = a_lds[g];
            const int rbase = i * BM;

            // feat groups kg 0..21 (kg=21 bridges 4 feat + 4 cos), kg-minor
            // for line-dense global reads (consecutive lanes = same row).
            for (int idx = tg; idx < BM * 22; idx += 256) {
                int slot = idx / 22, kg = idx - slot * 22;
                unsigned p = pt[rbase + slot];
                float tm = tsm[rbase + slot];
                float4 fa = make_float4(0.f, 0.f, 0.f, 0.f);
                float4 fb = fa;
                if (p != 0xFFFFu) {
                    const float4* src = (const float4*)feats + (base_e + (p & 0xFF)) * 43;
                    fa = src[2 * kg];
                    if (kg < 21) fb = src[2 * kg + 1];
                }
                s16x8 v;
                v[0] = (short)f2bf(fa.x); v[1] = (short)f2bf(fa.y);
                v[2] = (short)f2bf(fa.z); v[3] = (short)f2bf(fa.w);
                if (kg < 21) {
                    v[4] = (short)f2bf(fb.x); v[5] = (short)f2bf(fb.y);
                    v[6] = (short)f2bf(fb.z); v[7] = (short)f2bf(fb.w);
                } else {
                    #pragma unroll
                    for (int q = 0; q < 4; ++q) {
                        float rev = tm * freq_lds[q];
                        float fr  = rev - floorf(rev);
                        v[4 + q] = (short)f2bf(__builtin_amdgcn_cosf(fr));
                    }
                }
                int s = kg >> 2, h = kg & 3;
                *(s16x8*)&A[(((slot >> 4) * NKS + s) * 64 + h * 16 + (slot & 15)) * 8] = v;
            }
            // cos full groups kg 22..33 (slot-minor: conflict-free writes)
            for (int idx = tg; idx < BM * 12; idx += 256) {
                int slot = idx & 31, gg = idx >> 5;
                float tm = tsm[rbase + slot];
                int kg = 22 + gg;
                int s = kg >> 2, h = kg & 3;
                int j0 = kg * 8 - FEAT;
                s16x8 v;
                #pragma unroll
                for (int q = 0; q < 8; ++q) {
                    float rev = tm * freq_lds[j0 + q];
                    float fr  = rev - floorf(rev);
                    v[q] = (short)f2bf(__builtin_amdgcn_cosf(fr));
                }
                *(s16x8*)&A[(((slot >> 4) * NKS + s) * 64 + h * 16 + (slot & 15)) * 8] = v;
            }
            // zero pad kg 34,35 (k 272..287)
            for (int idx = tg; idx < BM * 2; idx += 256) {
                int slot = idx & 31, gg = idx >> 5;
                int kg = 34 + gg;
                int s = kg >> 2, h = kg & 3;
                s16x8 v = (s16x8){0, 0, 0, 0, 0, 0, 0, 0};
                *(s16x8*)&A[(((slot >> 4) * NKS + s) * 64 + h * 16 + (slot & 15)) * 8] = v;
            }
        }
        // ================= MFMA subtile i-1 (group (i-1)&1) =================
        if (i >= 1 && ((i - 1) & 1) == g) {
            const unsigned short* A = a_lds[g];
            const int rbase = (i - 1) * BM;
            const int mask = um[i - 1];
            f32x4 acc[2][2];
            #pragma unroll 1
            for (int t = 0; t < NT; ++t) {
                if (!((mask >> t) & 1)) continue;
                #pragma unroll
                for (int rb = 0; rb < 2; ++rb) {
                    acc[rb][0] = (f32x4){0.f, 0.f, 0.f, 0.f};
                    acc[rb][1] = (f32x4){0.f, 0.f, 0.f, 0.f};
                }
                const s16x8* bp = (const s16x8*)bfrag + (size_t)t * NKS * 8 * 64;
                // software-pipelined B: prefetch next s-step before using current
                s16x8 nb0 = bp[(2 * w + 0) * 64 + lane];
                s16x8 nb1 = bp[(2 * w + 1) * 64 + lane];
                #pragma unroll 1
                for (int s = 0; s < NKS; ++s) {
                    s16x8 b0 = nb0, b1 = nb1;
                    if (s + 1 < NKS) {
                        nb0 = bp[((s + 1) * 8 + 2 * w + 0) * 64 + lane];
                        nb1 = bp[((s + 1) * 8 + 2 * w + 1) * 64 + lane];
                    }
                    bf16x8 bb0 = __builtin_bit_cast(bf16x8, b0);
                    bf16x8 bb1 = __builtin_bit_cast(bf16x8, b1);
                    #pragma unroll
                    for (int rb = 0; rb < 2; ++rb) {
                        s16x8 araw = *(const s16x8*)&A[((rb * NKS + s) * 64 + lane) * 8];
                        bf16x8 a = __builtin_bit_cast(bf16x8, araw);
                        acc[rb][0] = __builtin_amdgcn_mfma_f32_16x16x32_bf16(a, bb0, acc[rb][0], 0, 0, 0);
                        acc[rb][1] = __builtin_amdgcn_mfma_f32_16x16x32_bf16(a, bb1, acc[rb][1], 0, 0, 0);
                    }
                }
                const float bias0 = bias_tab[t * OUTD + col0];
                const float bias1 = bias_tab[t * OUTD + col1];
                #pragma unroll
                for (int rb = 0; rb < 2; ++rb)
                    #pragma unroll
                    for (int rg = 0; rg < 4; ++rg) {
                        unsigned p = pt[rbase + rb * 16 + hq * 4 + rg];
                        if ((int)(p >> 12) == t) {
                            long e = base_e + (p & 0xFF);
                            out[(size_t)e * OUTD + col0] = acc[rb][0][rg] + bias0;
                            out[(size_t)e * OUTD + col1] = acc[rb][1][rg] + bias1;
                        }
                    }
            }
        }
        __syncthreads();
    }
}

// ---------------- launch ----------------
extern "C" void kernel_launch(void* const* d_in, const int* in_sizes, int n_in,
                              void* d_out, int out_size, void* d_ws, size_t ws_size,
                              hipStream_t stream) {
    const float* feats = (const float*)d_in[0];
    const float* ts    = (const float*)d_in[1];
    const int*   types = (const int*)d_in[2];
    const float* W     = (const float*)d_in[3];
    const float* b     = (const float*)d_in[4];
    const float* temb  = (const float*)d_in[5];
    float* out = (float*)d_out;
    const int E = in_sizes[1];

    char* ws = (char*)d_ws;
    auto align256 = [](size_t x) { return (x + 255) & ~(size_t)255; };
    int* flag = (int*)(ws + 0);
    size_t o = 256;
    float* freq_base = (float*)(ws + o); o = align256(o + TD * 4);
    float* bias      = (float*)(ws + o); o = align256(o + NT * OUTD * 4);
    unsigned short* bfrag = (unsigned short*)(ws + o);
    o = align256(o + (size_t)NT * NKS * 8 * 64 * 8 * 2);
    if (ws_size < o) return;   // never expected; prior rounds confirm ws is ample

    k_detect<<<1, 256, 0, stream>>>(types, flag);
    k_prep_tables<<<8, 256, 0, stream>>>(b, temb, freq_base, bias);
    k_prep_bfrag<<<(NT * NKS * 8 * 64 + 255) / 256, 256, 0, stream>>>(W, bfrag);

    int nblocks = (E + WIN - 1) / WIN;
    k_main<<<nblocks, 512, 0, stream>>>(feats, ts, types, flag, out,
                                        freq_base, bias, bfrag, E);
}

// Round 13
// 210.883 us; speedup vs baseline: 1.0922x; 1.0922x over previous
//
#include <hip/hip_runtime.h>
#include <hip/hip_bf16.h>

#define NT      8
#define TD      100
#define FEAT    172
#define DIN     272     // FEAT + TD
#define KPAD    288     // padded K, 9 * 32
#define NKS     9       // KPAD / 32
#define OUTD    128
#define BM      32      // rows per MFMA sub-tile (2 rowblocks of 16)
#define WIN     512     // edges per block (16 sub-tiles)
#define NST     (WIN / BM)
#define TWO_PI  6.283185307179586

typedef __bf16 bf16x8 __attribute__((ext_vector_type(8)));
typedef float  f32x4  __attribute__((ext_vector_type(4)));
typedef short  s16x8  __attribute__((ext_vector_type(8)));

__device__ __forceinline__ unsigned short f2bf(float f) {
    __hip_bfloat16 h = __float2bfloat16(f);        // 1-op HW convert (RNE)
    return __builtin_bit_cast(unsigned short, h);
}

// ---------------- dtype detection (int32 vs int64 edge_types) ----------------
__global__ void k_detect(const int* __restrict__ words, int* __restrict__ flag) {
    __shared__ int s_or;
    if (threadIdx.x == 0) s_or = 0;
    __syncthreads();
    int v  = words[2 * threadIdx.x + 1];
    int v2 = words[2 * (threadIdx.x + 256) + 1];
    if (v | v2) atomicOr(&s_or, 1);
    __syncthreads();
    if (threadIdx.x == 0) *flag = (s_or == 0) ? 1 : 0;   // 1 => int64
}

__device__ __forceinline__ int get_type(const int* __restrict__ p, int e, int is64) {
    return p[is64 ? (2 * e) : e] & 7;
}

// ---------------- table prep ----------------
__global__ void k_prep_tables(const float* __restrict__ b, const float* __restrict__ temb,
                              float* __restrict__ freq_base, float* __restrict__ bias) {
    int gid = blockIdx.x * blockDim.x + threadIdx.x;
    if (gid < TD)
        freq_base[gid] = (float)(pow(10.0, -(double)gid / 11.0) / TWO_PI);
    if (gid < NT * OUTD) bias[gid] = b[gid] + temb[gid];
}

// W[t][k][n] fp32 -> bf16 fragment order: bfrag[(((t*NKS+s)*8+nf)*64+lane)*8+i]
// lane: col = nf*16 + (lane&15), k = s*32 + (lane>>4)*8 + i   [HW-verified R3/R6]
__global__ void k_prep_bfrag(const float* __restrict__ W, unsigned short* __restrict__ bfrag) {
    int gid = blockIdx.x * blockDim.x + threadIdx.x;
    if (gid >= NT * NKS * 8 * 64) return;
    int lane = gid & 63;
    int rest = gid >> 6;
    int nf = rest & 7; rest >>= 3;
    int s = rest % NKS, t = rest / NKS;
    int n  = nf * 16 + (lane & 15);
    int kb = s * 32 + (lane >> 4) * 8;
    unsigned short v[8];
    #pragma unroll
    for (int i = 0; i < 8; ++i) {
        int k = kb + i;
        float x = (k < DIN) ? W[((size_t)t * DIN + k) * OUTD + n] : 0.0f;
        v[i] = f2bf(x);
    }
    unsigned short* dst = bfrag + (size_t)gid * 8;
    #pragma unroll
    for (int i = 0; i < 8; ++i) dst[i] = v[i];
}

// ---------------- main kernel ----------------
// Window = 512 consecutive edges, counting-sorted by type in LDS.
// 16 sub-tiles of 32 rows, double-buffered LDS; per step:
//   issue global loads (subtile i+1) -> regs ; MFMA (subtile i, all 8 waves,
//   B preloaded into 36 VGPRs per pass) ; cvt+ds_write (subtile i+1) ; barrier.
__global__ __launch_bounds__(512, 4) void k_main(
    const float* __restrict__ feats, const float* __restrict__ ts,
    const int* __restrict__ types, const int* __restrict__ flag,
    float* __restrict__ out, const float* __restrict__ freq_base,
    const float* __restrict__ bias_tab, const unsigned short* __restrict__ bfrag,
    int E)
{
    __shared__ __align__(16) unsigned short a_lds[2][2 * NKS * 64 * 8]; // 2x18432 B
    __shared__ unsigned short pt[WIN];   // local_idx(9b) | type<<12 ; 0xFFFF invalid
    __shared__ float tsm[WIN];           // ts[e] * (1 + 0.1*t), by sorted slot
    __shared__ float freq_lds[TD];
    __shared__ int cnt[NT];
    __shared__ int seg[NT + 1];
    __shared__ int um[NST];              // per-sub-tile type union mask

    const int tid = threadIdx.x;
    const long base_e = (long)blockIdx.x * WIN;
    const int is64 = *flag;

    if (tid < NT)  cnt[tid] = 0;
    if (tid < NST) um[tid] = 0;
    if (tid < TD)  freq_lds[tid] = freq_base[tid];
    pt[tid] = 0xFFFF;
    tsm[tid] = 0.0f;
    __syncthreads();

    // counting sort: 1 edge/thread
    int t0 = -1; float f0 = 0.f;
    {
        long e0 = base_e + tid;
        if (e0 < (long)E) {
            t0 = get_type(types, (int)e0, is64);
            f0 = ts[e0] * (1.0f + 0.1f * (float)t0);
            atomicAdd(&cnt[t0], 1);
        }
    }
    __syncthreads();
    if (tid == 0) {
        int a = 0;
        #pragma unroll
        for (int t = 0; t < NT; ++t) { seg[t] = a; a += cnt[t]; cnt[t] = 0; }
        seg[NT] = a;
    }
    __syncthreads();
    if (t0 >= 0) {
        int r = seg[t0] + atomicAdd(&cnt[t0], 1);
        pt[r] = (unsigned short)(tid | (t0 << 12));
        tsm[r] = f0;
        atomicOr(&um[r >> 5], 1 << t0);
    }
    __syncthreads();

    // zero pad region (k 272..287, s=8, h=2..3) once per buffer — never rewritten
    if (tid < 128) {
        int bufi = (tid >> 6) & 1, c = tid & 63;
        int rb = (c >> 5) & 1, h = 2 + ((c >> 4) & 1), sl = c & 15;
        s16x8 z = (s16x8){0, 0, 0, 0, 0, 0, 0, 0};
        *(s16x8*)&a_lds[bufi][((rb * NKS + 8) * 64 + h * 16 + sl) * 8] = z;
    }

    const int w = tid >> 6, lane = tid & 63;
    const int hq = lane >> 4, l15 = lane & 15;
    const int col = w * 16 + l15;                 // nf = w (8 waves x 16 cols)

    // staging cell assignment (slot-minor: conflict-free LDS writes)
    const int slotA = tid & 31, kgA = tid >> 5;   // kg 0..15, always valid
    const int kgB   = 16 + (tid >> 5);            // kg 16..21, valid iff tid < 192
    const bool hasB = (tid < 192);
    const bool hasC = (tid < 384);                // cos cells: slot=tid&31, kg=22+(tid>>5)

    float4 fa0, fb0, fa1, fb1;

    #pragma unroll 1
    for (int i = 0; i <= NST; ++i) {
        // ---- phase 1: issue global loads for subtile i (into regs, no wait)
        unsigned pA = 0xFFFFu, pB = 0xFFFFu;
        if (i < NST) {
            const int rbase = i * BM;
            pA = pt[rbase + slotA];
            fa0 = make_float4(0.f, 0.f, 0.f, 0.f); fb0 = fa0;
            if (pA != 0xFFFFu) {
                const float4* src = (const float4*)feats + (base_e + (pA & 0x1FF)) * 43;
                fa0 = src[2 * kgA]; fb0 = src[2 * kgA + 1];
            }
            if (hasB) {
                pB = pt[rbase + slotA];   // same slot, different kg
                fa1 = make_float4(0.f, 0.f, 0.f, 0.f); fb1 = fa1;
                if (pB != 0xFFFFu) {
                    const float4* src = (const float4*)feats + (base_e + (pB & 0x1FF)) * 43;
                    fa1 = src[2 * kgB];
                    if (kgB < 21) fb1 = src[2 * kgB + 1];
                }
            }
        }

        // ---- phase 2: MFMA subtile i-1 (reads buf[(i-1)&1])
        if (i >= 1) {
            const unsigned short* A = a_lds[(i - 1) & 1];
            const int rbase = (i - 1) * BM;
            const int mask = um[i - 1];
            if (mask) {
                // hoist row metadata (t-independent)
                unsigned pm0[4], pm1[4];
                #pragma unroll
                for (int rg = 0; rg < 4; ++rg) {
                    pm0[rg] = pt[rbase + hq * 4 + rg];
                    pm1[rg] = pt[rbase + 16 + hq * 4 + rg];
                }
                #pragma unroll 1
                for (int t = 0; t < NT; ++t) {
                    if (!((mask >> t) & 1)) continue;
                    // preload all 9 B fragments for nf = w into regs
                    const s16x8* bp = (const s16x8*)bfrag + ((size_t)t * NKS * 8 + w) * 64 + lane;
                    s16x8 breg[NKS];
                    #pragma unroll
                    for (int s = 0; s < NKS; ++s) breg[s] = bp[s * 8 * 64];
                    f32x4 acc0 = (f32x4){0.f, 0.f, 0.f, 0.f};
                    f32x4 acc1 = (f32x4){0.f, 0.f, 0.f, 0.f};
                    #pragma unroll
                    for (int s = 0; s < NKS; ++s) {
                        bf16x8 bb = __builtin_bit_cast(bf16x8, breg[s]);
                        s16x8 a0 = *(const s16x8*)&A[((0 * NKS + s) * 64 + lane) * 8];
                        s16x8 a1 = *(const s16x8*)&A[((1 * NKS + s) * 64 + lane) * 8];
                        acc0 = __builtin_amdgcn_mfma_f32_16x16x32_bf16(
                            __builtin_bit_cast(bf16x8, a0), bb, acc0, 0, 0, 0);
                        acc1 = __builtin_amdgcn_mfma_f32_16x16x32_bf16(
                            __builtin_bit_cast(bf16x8, a1), bb, acc1, 0, 0, 0);
                    }
                    const float bias = bias_tab[t * OUTD + col];
                    #pragma unroll
                    for (int rg = 0; rg < 4; ++rg) {
                        if ((int)(pm0[rg] >> 12) == t)
                            out[(size_t)(base_e + (pm0[rg] & 0x1FF)) * OUTD + col] = acc0[rg] + bias;
                        if ((int)(pm1[rg] >> 12) == t)
                            out[(size_t)(base_e + (pm1[rg] & 0x1FF)) * OUTD + col] = acc1[rg] + bias;
                    }
                }
            }
        }

        // ---- phase 3: cvt + LDS write subtile i (buf[i&1]); loads land under MFMA
        if (i < NST) {
            unsigned short* A = (unsigned short*)a_lds[i & 1];
            const int rbase = i * BM;
            {   // cell A: kg 0..15, pure feat
                s16x8 v;
                v[0] = (short)f2bf(fa0.x); v[1] = (short)f2bf(fa0.y);
                v[2] = (short)f2bf(fa0.z); v[3] = (short)f2bf(fa0.w);
                v[4] = (short)f2bf(fb0.x); v[5] = (short)f2bf(fb0.y);
                v[6] = (short)f2bf(fb0.z); v[7] = (short)f2bf(fb0.w);
                int s = kgA >> 2, h = kgA & 3;
                *(s16x8*)&A[(((slotA >> 4) * NKS + s) * 64 + h * 16 + (slotA & 15)) * 8] = v;
            }
            if (hasB) {  // cell B: kg 16..21 (kg=21 bridges 4 feat + 4 cos)
                s16x8 v;
                v[0] = (short)f2bf(fa1.x); v[1] = (short)f2bf(fa1.y);
                v[2] = (short)f2bf(fa1.z); v[3] = (short)f2bf(fa1.w);
                if (kgB < 21) {
                    v[4] = (short)f2bf(fb1.x); v[5] = (short)f2bf(fb1.y);
                    v[6] = (short)f2bf(fb1.z); v[7] = (short)f2bf(fb1.w);
                } else {
                    float tm = tsm[rbase + slotA];
                    #pragma unroll
                    for (int q = 0; q < 4; ++q) {
                        float rev = tm * freq_lds[q];
                        float fr  = rev - floorf(rev);
                        v[4 + q] = (short)f2bf(__builtin_amdgcn_cosf(fr));
                    }
                }
                int s = kgB >> 2, h = kgB & 3;
                *(s16x8*)&A[(((slotA >> 4) * NKS + s) * 64 + h * 16 + (slotA & 15)) * 8] = v;
            }
            if (hasC) {  // cos cells: kg 22..33 (j = 4..99)
                int slot = tid & 31, kg = 22 + (tid >> 5);
                float tm = tsm[rbase + slot];
                int j0 = kg * 8 - FEAT;
                s16x8 v;
                #pragma unroll
                for (int q = 0; q < 8; ++q) {
                    float rev = tm * freq_lds[j0 + q];
                    float fr  = rev - floorf(rev);
                    v[q] = (short)f2bf(__builtin_amdgcn_cosf(fr));
                }
                int s = kg >> 2, h = kg & 3;
                *(s16x8*)&A[(((slot >> 4) * NKS + s) * 64 + h * 16 + (slot & 15)) * 8] = v;
            }
        }
        __syncthreads();
    }
}

// ---------------- launch ----------------
extern "C" void kernel_launch(void* const* d_in, const int* in_sizes, int n_in,
                              void* d_out, int out_size, void* d_ws, size_t ws_size,
                              hipStream_t stream) {
    const float* feats = (const float*)d_in[0];
    const float* ts    = (const float*)d_in[1];
    const int*   types = (const int*)d_in[2];
    const float* W     = (const float*)d_in[3];
    const float* b     = (const float*)d_in[4];
    const float* temb  = (const float*)d_in[5];
    float* out = (float*)d_out;
    const int E = in_sizes[1];

    char* ws = (char*)d_ws;
    auto align256 = [](size_t x) { return (x + 255) & ~(size_t)255; };
    int* flag = (int*)(ws + 0);
    size_t o = 256;
    float* freq_base = (float*)(ws + o); o = align256(o + TD * 4);
    float* bias      = (float*)(ws + o); o = align256(o + NT * OUTD * 4);
    unsigned short* bfrag = (unsigned short*)(ws + o);
    o = align256(o + (size_t)NT * NKS * 8 * 64 * 8 * 2);
    if (ws_size < o) return;

    k_detect<<<1, 256, 0, stream>>>(types, flag);
    k_prep_tables<<<8, 256, 0, stream>>>(b, temb, freq_base, bias);
    k_prep_bfrag<<<(NT * NKS * 8 * 64 + 255) / 256, 256, 0, stream>>>(W, bfrag);

    int nblocks = (E + WIN - 1) / WIN;
    k_main<<<nblocks, 512, 0, stream>>>(feats, ts, types, flag, out,
                                        freq_base, bias, bfrag, E);
}